// Round 10
// baseline (276.483 us; speedup 1.0000x reference)
//
#include <hip/hip_runtime.h>
#include <hip/hip_bf16.h>

// GAT-style graph attention. N=50000, E=600000, FEAT=128, H=8, D=16.
// R10: convert_x deleted (qkv reads fp32 X, in-register bf16 cvt);
//      recip kernel deleted (gather uses v_rcp inline). Otherwise R9:
//      dest-CSR, shfl-free sumexp, bf16 wraw, persistent-B MFMA GEMMs.

#define FEAT 128
#define NHEAD 8
#define NPAD 50048   // N rounded up to multiple of 64

typedef __attribute__((ext_vector_type(8))) short bf16x8;
typedef __attribute__((ext_vector_type(4))) float f32x4;

__device__ __forceinline__ unsigned short f2bf(float f) {
    unsigned u = __float_as_uint(f);
    u += 0x7fffu + ((u >> 16) & 1u);
    return (unsigned short)(u >> 16);
}
__device__ __forceinline__ float bf2f_lo(unsigned u) { return __uint_as_float(u << 16); }
__device__ __forceinline__ float bf2f_hi(unsigned u) { return __uint_as_float(u & 0xffff0000u); }
__device__ __forceinline__ float bfw(unsigned short u) { return __uint_as_float((unsigned)u << 16); }

// ---- fused prep: dest histogram | convert_w ----
__global__ __launch_bounds__(256) void prep_kernel(
    const int* __restrict__ dsts, int* __restrict__ counts,
    const float* __restrict__ Wq, const float* __restrict__ Wk,
    const float* __restrict__ Wv, const float* __restrict__ Wo,
    unsigned short* __restrict__ Wb,
    int E, int histBlocks)
{
    int b = blockIdx.x;
    if (b < histBlocks) {
        int e = b * 256 + threadIdx.x;
        if (e < E) atomicAdd(counts + dsts[e], 1);
        return;
    }
    b -= histBlocks;
    int i = b * 256 + threadIdx.x;
    if (i >= 4 * 2048) return;
    int mat = i >> 11, idx = i & 2047;
    const float* W = (mat == 0) ? Wq : (mat == 1) ? Wk : (mat == 2) ? Wv : Wo;
    const float4* xp = (const float4*)W + (size_t)idx * 2;
    float4 x0 = xp[0], x1 = xp[1];
    uint4 o;
    o.x = (unsigned)f2bf(x0.x) | ((unsigned)f2bf(x0.y) << 16);
    o.y = (unsigned)f2bf(x0.z) | ((unsigned)f2bf(x0.w) << 16);
    o.z = (unsigned)f2bf(x1.x) | ((unsigned)f2bf(x1.y) << 16);
    o.w = (unsigned)f2bf(x1.z) | ((unsigned)f2bf(x1.w) << 16);
    ((uint4*)(Wb + (size_t)mat * 16384))[idx] = o;
}

// ---- exclusive scan over N dest-counts ----
__global__ __launch_bounds__(256) void scan1_kernel(
    const int* __restrict__ counts, int* __restrict__ offsets,
    int* __restrict__ blocksums, int NT)
{
    __shared__ int buf[256];
    int t = threadIdx.x, i = blockIdx.x * 256 + t;
    int v = (i < NT) ? counts[i] : 0;
    buf[t] = v; __syncthreads();
    int x = v;
    #pragma unroll
    for (int off = 1; off < 256; off <<= 1) {
        int y = (t >= off) ? buf[t - off] : 0;
        __syncthreads();
        x += y; buf[t] = x;
        __syncthreads();
    }
    if (i < NT) offsets[i] = x - v;
    if (t == 255) blocksums[blockIdx.x] = x;
}

__global__ __launch_bounds__(256) void scan2_kernel(
    int* __restrict__ blocksums, int* __restrict__ blockoffs, int NB)
{
    __shared__ int buf[256];
    int t = threadIdx.x;
    int v = (t < NB) ? blocksums[t] : 0;
    buf[t] = v; __syncthreads();
    int x = v;
    #pragma unroll
    for (int off = 1; off < 256; off <<= 1) {
        int y = (t >= off) ? buf[t - off] : 0;
        __syncthreads();
        x += y; buf[t] = x;
        __syncthreads();
    }
    if (t < NB) blockoffs[t] = x - v;
}

__global__ __launch_bounds__(256) void scan3_kernel(
    int* __restrict__ offsets, const int* __restrict__ blockoffs,
    int* __restrict__ cursor, int NT)
{
    int i = blockIdx.x * 256 + threadIdx.x;
    if (i < NT) {
        int o = offsets[i] + blockoffs[blockIdx.x];
        offsets[i] = o;
        cursor[i] = o;
    }
}

// ---- fill dest-CSR: ONE scattered 4B stream ----
__global__ __launch_bounds__(256) void fill_kernel(
    const int* __restrict__ srcs, const int* __restrict__ dsts,
    int* __restrict__ cursor, int* __restrict__ rec, int E)
{
    int e = blockIdx.x * 256 + threadIdx.x;
    if (e < E) {
        int s = srcs[e], d = dsts[e];
        int pd = atomicAdd(cursor + d, 1);
        __builtin_nontemporal_store(s, rec + pd);
    }
}

// ---- QKV MFMA GEMM: fp32 X read + in-register bf16 cvt; wave owns
//      32-col strip, B frags persistent in regs, grid-stride tiles ----
__global__ __launch_bounds__(256) void qkv_mfma_kernel(
    const float* __restrict__ X, const unsigned short* __restrict__ Wb,
    const float* __restrict__ bq, const float* __restrict__ bk, const float* __restrict__ bv,
    unsigned short* __restrict__ Q, unsigned short* __restrict__ K,
    unsigned short* __restrict__ V, int N, int numTiles)
{
    const int lane = threadIdx.x & 63;
    const int wave = threadIdx.x >> 6;
    const int m = lane & 15, quad = lane >> 4;
    const int colbase = wave * 32;

    bf16x8 bfr[3][2][4];
    #pragma unroll
    for (int mat = 0; mat < 3; mat++)
        #pragma unroll
        for (int ctl = 0; ctl < 2; ctl++) {
            const unsigned short* wrow =
                Wb + mat * 16384 + (size_t)(colbase + ctl * 16 + m) * FEAT + quad * 8;
            #pragma unroll
            for (int kc = 0; kc < 4; kc++)
                bfr[mat][ctl][kc] = *(const bf16x8*)(wrow + kc * 32);
        }

    const float* bias_p[3] = {bq, bk, bv};
    float bias[3][2];
    #pragma unroll
    for (int mat = 0; mat < 3; mat++)
        #pragma unroll
        for (int ctl = 0; ctl < 2; ctl++)
            bias[mat][ctl] = bias_p[mat][colbase + ctl * 16 + m];

    unsigned short* outp[3] = {Q, K, V};

    for (int tile = blockIdx.x; tile < numTiles; tile += gridDim.x) {
        const int row0 = tile * 16;
        const int arow_i = row0 + m;
        const float* arow = X + (size_t)(arow_i < N ? arow_i : N - 1) * FEAT + quad * 8;
        bf16x8 a[4];
        #pragma unroll
        for (int kc = 0; kc < 4; kc++) {
            float4 f0 = *(const float4*)(arow + kc * 32);
            float4 f1 = *(const float4*)(arow + kc * 32 + 4);
            bf16x8 t;
            t[0] = (short)f2bf(f0.x); t[1] = (short)f2bf(f0.y);
            t[2] = (short)f2bf(f0.z); t[3] = (short)f2bf(f0.w);
            t[4] = (short)f2bf(f1.x); t[5] = (short)f2bf(f1.y);
            t[6] = (short)f2bf(f1.z); t[7] = (short)f2bf(f1.w);
            a[kc] = t;
        }
        f32x4 acc[3][2];
        #pragma unroll
        for (int mat = 0; mat < 3; mat++)
            #pragma unroll
            for (int ctl = 0; ctl < 2; ctl++) acc[mat][ctl] = (f32x4){0.f, 0.f, 0.f, 0.f};
        #pragma unroll
        for (int kc = 0; kc < 4; kc++)
            #pragma unroll
            for (int mat = 0; mat < 3; mat++)
                #pragma unroll
                for (int ctl = 0; ctl < 2; ctl++)
                    acc[mat][ctl] = __builtin_amdgcn_mfma_f32_16x16x32_bf16(
                        a[kc], bfr[mat][ctl][kc], acc[mat][ctl], 0, 0, 0);
        #pragma unroll
        for (int mat = 0; mat < 3; mat++)
            #pragma unroll
            for (int ctl = 0; ctl < 2; ctl++)
                #pragma unroll
                for (int reg = 0; reg < 4; reg++) {
                    int row = row0 + quad * 4 + reg;
                    if (row < N)
                        outp[mat][(size_t)row * FEAT + colbase + ctl * 16 + m] =
                            f2bf(acc[mat][ctl][reg] + bias[mat][ctl]);
                }
    }
}

// ---- sumexp: one wave per DEST node, shfl-free (R9) ----
__global__ __launch_bounds__(256) void sumexp_kernel(
    const int* __restrict__ offsets, const int* __restrict__ counts,
    const int* __restrict__ rec,
    const unsigned short* __restrict__ Q, const unsigned short* __restrict__ K,
    unsigned short* __restrict__ wrawb, float* __restrict__ segsum, int N)
{
    int node = blockIdx.x * 4 + (threadIdx.x >> 6);
    if (node >= N) return;
    int lane = threadIdx.x & 63;
    int j = lane >> 3, h = lane & 7;
    int start = offsets[node], deg = counts[node];
    if (deg == 0) return;

    float kf[16];
    {
        const unsigned* kp = (const unsigned*)(K + (size_t)node * FEAT + h * 16);
        #pragma unroll
        for (int i = 0; i < 8; i++) {
            unsigned u = kp[i];
            kf[2 * i]     = bf2f_lo(u);
            kf[2 * i + 1] = bf2f_hi(u);
        }
    }

    for (int j0 = 0; j0 < deg; j0 += 8) {
        int jj = j0 + j;
        bool act = jj < deg;
        int pos = start + (act ? jj : j0);
        int s = rec[pos];
        const unsigned* qp = (const unsigned*)(Q + (size_t)s * FEAT + h * 16);
        uint4 qa = *(const uint4*)qp;
        uint4 qb = *(const uint4*)(qp + 4);
        float p;
        p  = bf2f_lo(qa.x) * kf[0]  + bf2f_hi(qa.x) * kf[1];
        p += bf2f_lo(qa.y) * kf[2]  + bf2f_hi(qa.y) * kf[3];
        p += bf2f_lo(qa.z) * kf[4]  + bf2f_hi(qa.z) * kf[5];
        p += bf2f_lo(qa.w) * kf[6]  + bf2f_hi(qa.w) * kf[7];
        p += bf2f_lo(qb.x) * kf[8]  + bf2f_hi(qb.x) * kf[9];
        p += bf2f_lo(qb.y) * kf[10] + bf2f_hi(qb.y) * kf[11];
        p += bf2f_lo(qb.z) * kf[12] + bf2f_hi(qb.z) * kf[13];
        p += bf2f_lo(qb.w) * kf[14] + bf2f_hi(qb.w) * kf[15];
        float w = __expf(p * 0.25f);
        if (act) {
            wrawb[(size_t)(start + j0) * NHEAD + lane] = f2bf(w);
            atomicAdd(segsum + (size_t)s * NHEAD + h, w);
        }
    }
}

// ---- gather: one wave per dest node; inline v_rcp(segsum[src]) ----
__global__ __launch_bounds__(256) void gather_kernel(
    const int* __restrict__ offsets, const int* __restrict__ counts,
    const int* __restrict__ rec, const unsigned short* __restrict__ wrawb,
    const float* __restrict__ segsum, const unsigned short* __restrict__ V,
    unsigned short* __restrict__ agg, int N)
{
    int node = blockIdx.x * 4 + (threadIdx.x >> 6);
    if (node >= N) return;
    int lane = threadIdx.x & 63;
    int h = lane >> 3;
    int start = offsets[node], deg = counts[node];
    float ax = 0.f, ay = 0.f;
    int j = 0;
    for (; j + 4 <= deg; j += 4) {
        int p = start + j;
        int s0 = rec[p], s1 = rec[p + 1];
        int s2 = rec[p + 2], s3 = rec[p + 3];
        float w0 = bfw(wrawb[(size_t)(p + 0) * NHEAD + h]) *
                   __builtin_amdgcn_rcpf(segsum[(size_t)s0 * NHEAD + h]);
        float w1 = bfw(wrawb[(size_t)(p + 1) * NHEAD + h]) *
                   __builtin_amdgcn_rcpf(segsum[(size_t)s1 * NHEAD + h]);
        float w2 = bfw(wrawb[(size_t)(p + 2) * NHEAD + h]) *
                   __builtin_amdgcn_rcpf(segsum[(size_t)s2 * NHEAD + h]);
        float w3 = bfw(wrawb[(size_t)(p + 3) * NHEAD + h]) *
                   __builtin_amdgcn_rcpf(segsum[(size_t)s3 * NHEAD + h]);
        unsigned v0 = *(const unsigned*)(V + (size_t)s0 * FEAT + lane * 2);
        unsigned v1 = *(const unsigned*)(V + (size_t)s1 * FEAT + lane * 2);
        unsigned v2 = *(const unsigned*)(V + (size_t)s2 * FEAT + lane * 2);
        unsigned v3 = *(const unsigned*)(V + (size_t)s3 * FEAT + lane * 2);
        ax += w0 * bf2f_lo(v0) + w1 * bf2f_lo(v1) + w2 * bf2f_lo(v2) + w3 * bf2f_lo(v3);
        ay += w0 * bf2f_hi(v0) + w1 * bf2f_hi(v1) + w2 * bf2f_hi(v2) + w3 * bf2f_hi(v3);
    }
    for (; j < deg; j++) {
        int p = start + j;
        int s = rec[p];
        float w = bfw(wrawb[(size_t)p * NHEAD + h]) *
                  __builtin_amdgcn_rcpf(segsum[(size_t)s * NHEAD + h]);
        unsigned v = *(const unsigned*)(V + (size_t)s * FEAT + lane * 2);
        ax += w * bf2f_lo(v);
        ay += w * bf2f_hi(v);
    }
    unsigned o = (unsigned)f2bf(ax) | ((unsigned)f2bf(ay) << 16);
    *(unsigned*)(agg + (size_t)node * FEAT + lane * 2) = o;
}

// ---- out MFMA GEMM: persistent-B structure, 1 matrix, f32 out ----
__global__ __launch_bounds__(256) void out_mfma_kernel(
    const unsigned short* __restrict__ Ab, const unsigned short* __restrict__ Wob,
    const float* __restrict__ bo, float* __restrict__ out, int N, int numTiles)
{
    const int lane = threadIdx.x & 63;
    const int wave = threadIdx.x >> 6;
    const int m = lane & 15, quad = lane >> 4;
    const int colbase = wave * 32;

    bf16x8 bfr[2][4];
    #pragma unroll
    for (int ctl = 0; ctl < 2; ctl++) {
        const unsigned short* wrow = Wob + (size_t)(colbase + ctl * 16 + m) * FEAT + quad * 8;
        #pragma unroll
        for (int kc = 0; kc < 4; kc++)
            bfr[ctl][kc] = *(const bf16x8*)(wrow + kc * 32);
    }
    float bias[2];
    #pragma unroll
    for (int ctl = 0; ctl < 2; ctl++) bias[ctl] = bo[colbase + ctl * 16 + m];

    for (int tile = blockIdx.x; tile < numTiles; tile += gridDim.x) {
        const int row0 = tile * 16;
        const unsigned short* arow = Ab + (size_t)(row0 + m) * FEAT + quad * 8;
        bf16x8 a[4];
        #pragma unroll
        for (int kc = 0; kc < 4; kc++) a[kc] = *(const bf16x8*)(arow + kc * 32);
        f32x4 acc[2];
        #pragma unroll
        for (int ctl = 0; ctl < 2; ctl++) acc[ctl] = (f32x4){0.f, 0.f, 0.f, 0.f};
        #pragma unroll
        for (int kc = 0; kc < 4; kc++)
            #pragma unroll
            for (int ctl = 0; ctl < 2; ctl++)
                acc[ctl] = __builtin_amdgcn_mfma_f32_16x16x32_bf16(
                    a[kc], bfr[ctl][kc], acc[ctl], 0, 0, 0);
        #pragma unroll
        for (int ctl = 0; ctl < 2; ctl++)
            #pragma unroll
            for (int reg = 0; reg < 4; reg++) {
                int row = row0 + quad * 4 + reg;
                if (row < N)
                    out[(size_t)row * FEAT + colbase + ctl * 16 + m] = acc[ctl][reg] + bias[ctl];
            }
    }
}

extern "C" void kernel_launch(void* const* d_in, const int* in_sizes, int n_in,
                              void* d_out, int out_size, void* d_ws, size_t ws_size,
                              hipStream_t stream) {
    const float* X  = (const float*)d_in[0];
    const int*   ei = (const int*)d_in[1];
    const float* Wq = (const float*)d_in[2];
    const float* bq = (const float*)d_in[3];
    const float* Wk = (const float*)d_in[4];
    const float* bk = (const float*)d_in[5];
    const float* Wv = (const float*)d_in[6];
    const float* bv = (const float*)d_in[7];
    const float* Wo = (const float*)d_in[8];
    const float* bo = (const float*)d_in[9];
    float* out = (float*)d_out;

    const int N = in_sizes[0] / FEAT;        // 50000
    const int E = in_sizes[1] / 2;           // 600000
    const int* srcs = ei;
    const int* dsts = ei + E;
    const size_t NF2 = (size_t)NPAD * FEAT * 2;

    char* w = (char*)d_ws;
    unsigned short* Qb = (unsigned short*)w;  w += NF2;
    unsigned short* Kb = (unsigned short*)w;  w += NF2;
    unsigned short* Vb = (unsigned short*)w;  w += NF2;
    unsigned short* Ab = (unsigned short*)w;  w += NF2;
    unsigned short* Wb = (unsigned short*)w;  w += (size_t)4 * 16384 * 2;
    unsigned short* wrawb = (unsigned short*)w; w += (size_t)E * NHEAD * 2;  // bf16
    float* segsum      = (float*)w;           w += (size_t)N * NHEAD * 4;  // zeroed
    int* counts        = (int*)w;             w += (size_t)N * 4;          // zeroed (contig)
    int* offsets       = (int*)w;             w += (size_t)N * 4;
    int* cursor        = (int*)w;             w += (size_t)N * 4;
    int* blocksums     = (int*)w;             w += 256 * 4;
    int* blockoffs     = (int*)w;             w += 256 * 4;
    int* rec           = (int*)w;             w += (size_t)E * 4;

    // zero segsum + counts (contiguous)
    hipMemsetAsync(segsum, 0, ((size_t)N * NHEAD + N) * sizeof(float), stream);

    int e_blocks = (E + 255) / 256;          // 2344
    prep_kernel<<<e_blocks + 32, 256, 0, stream>>>(
        dsts, counts, Wq, Wk, Wv, Wo, Wb, E, e_blocks);

    int NB = (N + 255) / 256;   // 196
    scan1_kernel<<<NB, 256, 0, stream>>>(counts, offsets, blocksums, N);
    scan2_kernel<<<1, 256, 0, stream>>>(blocksums, blockoffs, NB);
    scan3_kernel<<<NB, 256, 0, stream>>>(offsets, blockoffs, cursor, N);

    fill_kernel<<<e_blocks, 256, 0, stream>>>(srcs, dsts, cursor, rec, E);

    int numTiles = NPAD / 16;   // 3128
    qkv_mfma_kernel<<<782, 256, 0, stream>>>(X, Wb, bq, bk, bv, Qb, Kb, Vb, N, numTiles);

    int node_blocks = (N + 3) / 4;
    sumexp_kernel<<<node_blocks, 256, 0, stream>>>(
        offsets, counts, rec, Qb, Kb, wrawb, segsum, N);

    gather_kernel<<<node_blocks, 256, 0, stream>>>(
        offsets, counts, rec, wrawb, segsum, Vb, Ab, N);

    out_mfma_kernel<<<782, 256, 0, stream>>>(Ab, Wb + 3 * 16384, bo, out, N, numTiles);
}